// Round 4
// baseline (1677.012 us; speedup 1.0000x reference)
//
#include <hip/hip_runtime.h>
#include <hip/hip_bf16.h>

#define N_ENT 40000
#define NB 64
#define BODY_LEN 3
#define N_REL 48
#define NUM_POS 24
#define THR 1e-20f
#define NBLK 1024
#define NTHR 256

// mem layout: entity-major, mem[ent*64 + b]
// edge pack: int4 {head, tail, rel, float_as_int(val_after_kill)}

// Software grid barrier: per-phase counters, never reset. Safe because
// __launch_bounds__(256,4) caps VGPR at 128 -> >=4 blocks/CU -> all 1024
// blocks co-resident (LDS 16.9KB*4 = 67.6KB < 160KB, 16 waves/CU <= 32).
__device__ __forceinline__ void gridbar(unsigned* bar, int phase) {
    __syncthreads();
    if (threadIdx.x == 0) {
        __threadfence();  // release: flush this block's writes device-wide
        __hip_atomic_fetch_add(&bar[phase], 1u, __ATOMIC_RELEASE, __HIP_MEMORY_SCOPE_AGENT);
        while (__hip_atomic_load(&bar[phase], __ATOMIC_ACQUIRE, __HIP_MEMORY_SCOPE_AGENT) < NBLK)
            __builtin_amdgcn_s_sleep(2);
    }
    __syncthreads();
    __threadfence();  // acquire: invalidate stale cache lines for all threads
}

template <bool STEP0>
__device__ __forceinline__ void scan_scatter(
    const int4* __restrict__ ep, const unsigned long long* __restrict__ act,
    const float* __restrict__ oldm, float* __restrict__ nxt,
    const float (*__restrict__ sattn)[N_REL + 1],
    int nE, int lane, int myqh, int wave, int nW) {
    int e = wave;
    for (; e + nW < nE; e += 2 * nW) {
        int4 E0 = ep[e];
        int4 E1 = ep[e + nW];
        float v0 = __int_as_float(E0.w), v1 = __int_as_float(E1.w);
        unsigned long long ah0 = 0, at0 = 0, ah1 = 0, at1 = 0;
        if (!STEP0) { ah0 = act[E0.x]; at0 = act[E0.y]; ah1 = act[E1.x]; at1 = act[E1.y]; }
        if (STEP0) {
            bool hh = (E0.x == myqh), ht = (E0.y == myqh);
            if (__ballot(hh || ht) != 0ULL && v0 != 0.0f) {
                float c1 = hh ? v0 * sattn[lane][E0.z] : 0.0f;
                float c2 = ht ? v0 * sattn[lane][E0.z + NUM_POS] : 0.0f;
                if (c1 != 0.0f) atomicAdd(&nxt[(size_t)E0.y * 64 + lane], c1);
                if (c2 != 0.0f) atomicAdd(&nxt[(size_t)E0.x * 64 + lane], c2);
            }
            hh = (E1.x == myqh); ht = (E1.y == myqh);
            if (__ballot(hh || ht) != 0ULL && v1 != 0.0f) {
                float c1 = hh ? v1 * sattn[lane][E1.z] : 0.0f;
                float c2 = ht ? v1 * sattn[lane][E1.z + NUM_POS] : 0.0f;
                if (c1 != 0.0f) atomicAdd(&nxt[(size_t)E1.y * 64 + lane], c1);
                if (c2 != 0.0f) atomicAdd(&nxt[(size_t)E1.x * 64 + lane], c2);
            }
        } else {
            if (((ah0 | at0) != 0ULL) && v0 != 0.0f) {
                bool hh = (ah0 >> lane) & 1ULL, ht = (at0 >> lane) & 1ULL;
                float c1 = hh ? oldm[(size_t)E0.x * 64 + lane] * v0 * sattn[lane][E0.z] : 0.0f;
                float c2 = ht ? oldm[(size_t)E0.y * 64 + lane] * v0 * sattn[lane][E0.z + NUM_POS] : 0.0f;
                if (c1 != 0.0f) atomicAdd(&nxt[(size_t)E0.y * 64 + lane], c1);
                if (c2 != 0.0f) atomicAdd(&nxt[(size_t)E0.x * 64 + lane], c2);
            }
            if (((ah1 | at1) != 0ULL) && v1 != 0.0f) {
                bool hh = (ah1 >> lane) & 1ULL, ht = (at1 >> lane) & 1ULL;
                float c1 = hh ? oldm[(size_t)E1.x * 64 + lane] * v1 * sattn[lane][E1.z] : 0.0f;
                float c2 = ht ? oldm[(size_t)E1.y * 64 + lane] * v1 * sattn[lane][E1.z + NUM_POS] : 0.0f;
                if (c1 != 0.0f) atomicAdd(&nxt[(size_t)E1.y * 64 + lane], c1);
                if (c2 != 0.0f) atomicAdd(&nxt[(size_t)E1.x * 64 + lane], c2);
            }
        }
    }
    for (; e < nE; e += nW) {
        int4 E = ep[e];
        float v = __int_as_float(E.w);
        if (STEP0) {
            bool hh = (E.x == myqh), ht = (E.y == myqh);
            if (__ballot(hh || ht) == 0ULL || v == 0.0f) continue;
            float c1 = hh ? v * sattn[lane][E.z] : 0.0f;
            float c2 = ht ? v * sattn[lane][E.z + NUM_POS] : 0.0f;
            if (c1 != 0.0f) atomicAdd(&nxt[(size_t)E.y * 64 + lane], c1);
            if (c2 != 0.0f) atomicAdd(&nxt[(size_t)E.x * 64 + lane], c2);
        } else {
            unsigned long long ah = act[E.x], at = act[E.y];
            if (((ah | at) == 0ULL) || v == 0.0f) continue;
            bool hh = (ah >> lane) & 1ULL, ht = (at >> lane) & 1ULL;
            float c1 = hh ? oldm[(size_t)E.x * 64 + lane] * v * sattn[lane][E.z] : 0.0f;
            float c2 = ht ? oldm[(size_t)E.y * 64 + lane] * v * sattn[lane][E.z + NUM_POS] : 0.0f;
            if (c1 != 0.0f) atomicAdd(&nxt[(size_t)E.y * 64 + lane], c1);
            if (c2 != 0.0f) atomicAdd(&nxt[(size_t)E.x * 64 + lane], c2);
        }
    }
}

__global__ __launch_bounds__(NTHR, 4) void k_all(
    const int* __restrict__ qh, const int* __restrict__ qr, const int* __restrict__ tt,
    const float* __restrict__ attn,
    const int* __restrict__ eh, const int* __restrict__ et, const int* __restrict__ er,
    const float* __restrict__ ev,
    int4* __restrict__ ep, float* __restrict__ sums, unsigned* __restrict__ bar,
    unsigned long long* __restrict__ act,
    float* __restrict__ memA, float* __restrict__ memB, float* __restrict__ out, int nE) {
    __shared__ __align__(16) unsigned char s_raw[(64 * 65 + 64) * 4];  // 16.9 KB

    const int tid = threadIdx.x;
    const int lane = tid & 63;
    const int gtid = blockIdx.x * NTHR + tid;
    const int gsz = NBLK * NTHR;          // 262144
    const int wave = gtid >> 6;
    const int nW = gsz >> 6;              // 4096
    const int total4 = NB * N_ENT / 4;    // 640000

    // ---- P0: kill-mask + pack edges; memA = D0 * one_hot(qh) ----
    {
        long long* s_key = (long long*)s_raw;
        float* s_d = (float*)(s_raw + 512);
        int* s_q = (int*)(s_raw + 512 + 256);
        if (tid < NB) {
            s_key[tid] = ((long long)qh[tid] << 32) | ((long long)tt[tid] << 8) | (long long)qr[tid];
            s_d[tid] = attn[tid * (BODY_LEN * N_REL) + 0 * N_REL + (N_REL - 1)];
            s_q[tid] = qh[tid];
        }
        __syncthreads();
        for (int i = gtid; i < nE; i += gsz) {
            int h = eh[i], t = et[i], r = er[i];
            long long k = ((long long)h << 32) | ((long long)t << 8) | (long long)r;
            bool killed = false;
#pragma unroll
            for (int b = 0; b < NB; ++b) killed |= (s_key[b] == k);
            float v = killed ? 0.0f : ev[i];
            ep[i] = make_int4(h, t, r, __float_as_int(v));
        }
        int b0 = (tid * 4) & 63;
        for (int i4 = gtid; i4 < total4; i4 += gsz) {
            int ent = i4 >> 4;
            float4 w;
            w.x = (s_q[b0 + 0] == ent) ? s_d[b0 + 0] : 0.0f;
            w.y = (s_q[b0 + 1] == ent) ? s_d[b0 + 1] : 0.0f;
            w.z = (s_q[b0 + 2] == ent) ? s_d[b0 + 2] : 0.0f;
            w.w = (s_q[b0 + 3] == ent) ? s_d[b0 + 3] : 0.0f;
            ((float4*)memA)[i4] = w;
        }
    }
    gridbar(bar, 0);

    // ---- P1: step-0 scatter (analytic one-hot gather) into memA ----
    {
        float(*sattn)[N_REL + 1] = (float(*)[N_REL + 1])s_raw;
        for (int idx = tid; idx < NB * N_REL; idx += NTHR) {
            int b = idx / N_REL, r = idx % N_REL;
            sattn[b][r] = attn[b * (BODY_LEN * N_REL) + 0 * N_REL + r];
        }
        __syncthreads();
        int myqh = qh[lane];
        scan_scatter<true>(ep, nullptr, nullptr, memA, sattn, nE, lane, myqh, wave, nW);
    }
    gridbar(bar, 1);

    for (int s = 1; s < BODY_LEN; ++s) {
        const float* cur = (s == 1) ? memA : memB;
        float* nxt = (s == 1) ? memB : memA;
        // ---- decay cur -> nxt; build per-entity 64-bit activity mask of cur ----
        {
            float* s_d = (float*)s_raw;
            if (tid < NB) s_d[tid] = attn[tid * (BODY_LEN * N_REL) + s * N_REL + (N_REL - 1)];
            __syncthreads();
            int b0 = (tid * 4) & 63;
            for (int i4 = gtid; i4 < total4; i4 += gsz) {
                float4 v = ((const float4*)cur)[i4];
                float4 w;
                w.x = v.x * s_d[b0 + 0];
                w.y = v.y * s_d[b0 + 1];
                w.z = v.z * s_d[b0 + 2];
                w.w = v.w * s_d[b0 + 3];
                ((float4*)nxt)[i4] = w;
                unsigned nib = (unsigned)(v.x != 0.0f) | ((unsigned)(v.y != 0.0f) << 1) |
                               ((unsigned)(v.z != 0.0f) << 2) | ((unsigned)(v.w != 0.0f) << 3);
                unsigned long long m = (unsigned long long)nib << (4 * (lane & 15));
#pragma unroll
                for (int off = 1; off < 16; off <<= 1)
                    m |= (unsigned long long)__shfl_xor((long long)m, off, 16);
                if ((lane & 15) == 0) act[i4 >> 4] = m;
            }
        }
        gridbar(bar, 2 * s);
        // ---- scatter: mask-gated gathers from cur, atomics into nxt ----
        {
            float(*sattn)[N_REL + 1] = (float(*)[N_REL + 1])s_raw;
            for (int idx = tid; idx < NB * N_REL; idx += NTHR) {
                int b = idx / N_REL, r = idx % N_REL;
                sattn[b][r] = attn[b * (BODY_LEN * N_REL) + s * N_REL + r];
            }
            __syncthreads();
            scan_scatter<false>(ep, act, cur, nxt, sattn, nE, lane, 0, wave, nW);
        }
        gridbar(bar, 2 * s + 1);
    }
    // final state in memA

    // ---- P6: per-batch sums (256 blocks only, to limit atomic contention) ----
    {
        float* s_s = (float*)s_raw;
        if (blockIdx.x < 256) {
            if (tid < NB) s_s[tid] = 0.0f;
            __syncthreads();
            float4 acc = {0.0f, 0.0f, 0.0f, 0.0f};
            int stride = 256 * NTHR;
            for (int i4 = blockIdx.x * NTHR + tid; i4 < total4; i4 += stride) {
                float4 v = ((const float4*)memA)[i4];
                acc.x += v.x; acc.y += v.y; acc.z += v.z; acc.w += v.w;
            }
            int b0 = (tid * 4) & 63;
            atomicAdd(&s_s[b0 + 0], acc.x);
            atomicAdd(&s_s[b0 + 1], acc.y);
            atomicAdd(&s_s[b0 + 2], acc.z);
            atomicAdd(&s_s[b0 + 3], acc.w);
            __syncthreads();
            if (tid < NB) atomicAdd(&sums[tid], s_s[tid]);
        }
    }
    gridbar(bar, 6);

    // ---- P7: transpose + normalize + loss ----
    {
        float(*tile)[65] = (float(*)[65])s_raw;
        float* s_inv = (float*)(s_raw + 64 * 65 * 4);
        if (blockIdx.x < N_ENT / 64) {
            int e0 = blockIdx.x * 64;
            if (tid < 64) s_inv[tid] = 1.0f / fmaxf(THR, sums[tid]);
            const float4* m4 = (const float4*)(memA + (size_t)e0 * 64);
#pragma unroll
            for (int k = 0; k < 4; ++k) {
                int i4 = k * 256 + tid;
                float4 v = m4[i4];
                int el = i4 >> 4, b0 = (i4 * 4) & 63;
                tile[el][b0 + 0] = v.x; tile[el][b0 + 1] = v.y;
                tile[el][b0 + 2] = v.z; tile[el][b0 + 3] = v.w;
            }
            __syncthreads();
#pragma unroll
            for (int k = 0; k < 16; ++k) {
                int idx = k * 256 + tid;
                int el = idx & 63, b = idx >> 6;
                out[1 + (size_t)b * N_ENT + e0 + el] = tile[el][b] * s_inv[b];
            }
        } else if (blockIdx.x == N_ENT / 64) {
            int b = tid;
            if (b < 64) {
                float p = memA[(size_t)tt[b] * 64 + b] / fmaxf(THR, sums[b]);
                float l = -logf(fmaxf(THR, p));
#pragma unroll
                for (int off = 32; off > 0; off >>= 1) l += __shfl_down(l, off);
                if (b == 0) out[0] = l * (1.0f / 64.0f);
            }
        }
    }
}

extern "C" void kernel_launch(void* const* d_in, const int* in_sizes, int n_in,
                              void* d_out, int out_size, void* d_ws, size_t ws_size,
                              hipStream_t stream) {
    const int*   qh   = (const int*)d_in[0];
    const int*   qr   = (const int*)d_in[1];
    const int*   tt   = (const int*)d_in[2];
    const float* attn = (const float*)d_in[3];
    const int*   eh   = (const int*)d_in[4];
    const int*   et   = (const int*)d_in[5];
    const int*   er   = (const int*)d_in[6];
    const float* ev   = (const float*)d_in[7];
    float* out = (float*)d_out;
    int nE = in_sizes[4];

    char* ws = (char*)d_ws;
    int4*               ep   = (int4*)ws;                                  // 4.8 MB
    float*              sums = (float*)(ws + (6u << 20));                  // 256 B
    unsigned*           bar  = (unsigned*)(ws + (6u << 20) + 256);         // 32 B (8 phases)
    unsigned long long* act  = (unsigned long long*)(ws + (6u << 20) + 4096);  // 320 KB
    float* memA = (float*)(ws + (8u << 20));                               // 10.24 MB
    float* memB = (float*)(ws + (8u << 20) + 10240000u);                   // 10.24 MB

    // zero sums + barrier counters (ws is re-poisoned to 0xAA before every launch)
    hipMemsetAsync(ws + (6u << 20), 0, 512, stream);

    k_all<<<NBLK, NTHR, 0, stream>>>(qh, qr, tt, attn, eh, et, er, ev,
                                     ep, sums, bar, act, memA, memB, out, nE);
}

// Round 5
// 1128.859 us; speedup vs baseline: 1.4856x; 1.4856x over previous
//
#include <hip/hip_runtime.h>
#include <hip/hip_bf16.h>

#define N_ENT 40000
#define NB 64
#define BODY_LEN 3
#define N_REL 48
#define NUM_POS 24
#define THR 1e-20f
#define NBLK 1024
#define NTHR 256

// mem layout: entity-major, mem[ent*64 + b]
// edge pack: int4 {head, tail, rel, float_as_int(val_after_kill)}

// Software grid barrier: per-phase counters, never reset. All 1024 blocks are
// co-resident (4 blocks/CU, verified by R4 occupancy=49%~16/32 waves). Spin
// uses RELAXED atomics (no per-poll cache invalidate); one release fence
// before arrival, one acquire fence after exit.
__device__ __forceinline__ void gridbar(unsigned* bar, int phase) {
    __syncthreads();
    if (threadIdx.x == 0) {
        __threadfence();  // release: writeback this XCD's L2 so others can see our writes
        __hip_atomic_fetch_add(&bar[phase], 1u, __ATOMIC_RELAXED, __HIP_MEMORY_SCOPE_AGENT);
        while (__hip_atomic_load(&bar[phase], __ATOMIC_RELAXED, __HIP_MEMORY_SCOPE_AGENT) < NBLK)
            __builtin_amdgcn_s_sleep(16);
    }
    __syncthreads();
    __threadfence();  // acquire: invalidate L1/L2 so we read other XCDs' writes
}

// Returns this lane's total scattered contribution (for the final-step sums).
template <bool STEP0>
__device__ __forceinline__ float scan_scatter(
    const int4* __restrict__ ep, const unsigned long long* __restrict__ act,
    const float* __restrict__ oldm, float* __restrict__ nxt,
    const float (*__restrict__ sattn)[N_REL + 1],
    int nE, int lane, int myqh, int wave, int nW) {
    float lsum = 0.0f;
    int e = wave;
    for (; e + nW < nE; e += 2 * nW) {
        int4 E0 = ep[e];
        int4 E1 = ep[e + nW];
        float v0 = __int_as_float(E0.w), v1 = __int_as_float(E1.w);
        unsigned long long ah0 = 0, at0 = 0, ah1 = 0, at1 = 0;
        if (!STEP0) { ah0 = act[E0.x]; at0 = act[E0.y]; ah1 = act[E1.x]; at1 = act[E1.y]; }
        if (STEP0) {
            bool hh = (E0.x == myqh), ht = (E0.y == myqh);
            if (__ballot(hh || ht) != 0ULL && v0 != 0.0f) {
                float c1 = hh ? v0 * sattn[lane][E0.z] : 0.0f;
                float c2 = ht ? v0 * sattn[lane][E0.z + NUM_POS] : 0.0f;
                if (c1 != 0.0f) atomicAdd(&nxt[(size_t)E0.y * 64 + lane], c1);
                if (c2 != 0.0f) atomicAdd(&nxt[(size_t)E0.x * 64 + lane], c2);
            }
            hh = (E1.x == myqh); ht = (E1.y == myqh);
            if (__ballot(hh || ht) != 0ULL && v1 != 0.0f) {
                float c1 = hh ? v1 * sattn[lane][E1.z] : 0.0f;
                float c2 = ht ? v1 * sattn[lane][E1.z + NUM_POS] : 0.0f;
                if (c1 != 0.0f) atomicAdd(&nxt[(size_t)E1.y * 64 + lane], c1);
                if (c2 != 0.0f) atomicAdd(&nxt[(size_t)E1.x * 64 + lane], c2);
            }
        } else {
            if (((ah0 | at0) != 0ULL) && v0 != 0.0f) {
                bool hh = (ah0 >> lane) & 1ULL, ht = (at0 >> lane) & 1ULL;
                float c1 = hh ? oldm[(size_t)E0.x * 64 + lane] * v0 * sattn[lane][E0.z] : 0.0f;
                float c2 = ht ? oldm[(size_t)E0.y * 64 + lane] * v0 * sattn[lane][E0.z + NUM_POS] : 0.0f;
                if (c1 != 0.0f) { atomicAdd(&nxt[(size_t)E0.y * 64 + lane], c1); lsum += c1; }
                if (c2 != 0.0f) { atomicAdd(&nxt[(size_t)E0.x * 64 + lane], c2); lsum += c2; }
            }
            if (((ah1 | at1) != 0ULL) && v1 != 0.0f) {
                bool hh = (ah1 >> lane) & 1ULL, ht = (at1 >> lane) & 1ULL;
                float c1 = hh ? oldm[(size_t)E1.x * 64 + lane] * v1 * sattn[lane][E1.z] : 0.0f;
                float c2 = ht ? oldm[(size_t)E1.y * 64 + lane] * v1 * sattn[lane][E1.z + NUM_POS] : 0.0f;
                if (c1 != 0.0f) { atomicAdd(&nxt[(size_t)E1.y * 64 + lane], c1); lsum += c1; }
                if (c2 != 0.0f) { atomicAdd(&nxt[(size_t)E1.x * 64 + lane], c2); lsum += c2; }
            }
        }
    }
    for (; e < nE; e += nW) {
        int4 E = ep[e];
        float v = __int_as_float(E.w);
        if (STEP0) {
            bool hh = (E.x == myqh), ht = (E.y == myqh);
            if (__ballot(hh || ht) == 0ULL || v == 0.0f) continue;
            float c1 = hh ? v * sattn[lane][E.z] : 0.0f;
            float c2 = ht ? v * sattn[lane][E.z + NUM_POS] : 0.0f;
            if (c1 != 0.0f) atomicAdd(&nxt[(size_t)E.y * 64 + lane], c1);
            if (c2 != 0.0f) atomicAdd(&nxt[(size_t)E.x * 64 + lane], c2);
        } else {
            unsigned long long ah = act[E.x], at = act[E.y];
            if (((ah | at) == 0ULL) || v == 0.0f) continue;
            bool hh = (ah >> lane) & 1ULL, ht = (at >> lane) & 1ULL;
            float c1 = hh ? oldm[(size_t)E.x * 64 + lane] * v * sattn[lane][E.z] : 0.0f;
            float c2 = ht ? oldm[(size_t)E.y * 64 + lane] * v * sattn[lane][E.z + NUM_POS] : 0.0f;
            if (c1 != 0.0f) { atomicAdd(&nxt[(size_t)E.y * 64 + lane], c1); lsum += c1; }
            if (c2 != 0.0f) { atomicAdd(&nxt[(size_t)E.x * 64 + lane], c2); lsum += c2; }
        }
    }
    return lsum;
}

__global__ __launch_bounds__(NTHR, 4) void k_all(
    const int* __restrict__ qh, const int* __restrict__ qr, const int* __restrict__ tt,
    const float* __restrict__ attn,
    const int* __restrict__ eh, const int* __restrict__ et, const int* __restrict__ er,
    const float* __restrict__ ev,
    int4* __restrict__ ep, float* __restrict__ sums, unsigned* __restrict__ bar,
    unsigned long long* __restrict__ act,
    float* __restrict__ memA, float* __restrict__ memB, float* __restrict__ out, int nE) {
    __shared__ __align__(16) unsigned char s_raw[(64 * 65 + 64) * 4];  // 16.9 KB

    const int tid = threadIdx.x;
    const int lane = tid & 63;
    const int gtid = blockIdx.x * NTHR + tid;
    const int gsz = NBLK * NTHR;          // 262144
    const int wave = gtid >> 6;
    const int nW = gsz >> 6;              // 4096
    const int total4 = NB * N_ENT / 4;    // 640000

    // ---- P0: kill-mask + pack edges; memA = D0 * one_hot(qh); zero sums ----
    {
        long long* s_key = (long long*)s_raw;
        float* s_d = (float*)(s_raw + 512);
        int* s_q = (int*)(s_raw + 512 + 256);
        if (tid < NB) {
            s_key[tid] = ((long long)qh[tid] << 32) | ((long long)tt[tid] << 8) | (long long)qr[tid];
            s_d[tid] = attn[tid * (BODY_LEN * N_REL) + 0 * N_REL + (N_REL - 1)];
            s_q[tid] = qh[tid];
        }
        if (gtid < NB) sums[gtid] = 0.0f;
        __syncthreads();
        for (int i = gtid; i < nE; i += gsz) {
            int h = eh[i], t = et[i], r = er[i];
            long long k = ((long long)h << 32) | ((long long)t << 8) | (long long)r;
            bool killed = false;
#pragma unroll
            for (int b = 0; b < NB; ++b) killed |= (s_key[b] == k);
            float v = killed ? 0.0f : ev[i];
            ep[i] = make_int4(h, t, r, __float_as_int(v));
        }
        int b0 = (tid * 4) & 63;
        for (int i4 = gtid; i4 < total4; i4 += gsz) {
            int ent = i4 >> 4;
            float4 w;
            w.x = (s_q[b0 + 0] == ent) ? s_d[b0 + 0] : 0.0f;
            w.y = (s_q[b0 + 1] == ent) ? s_d[b0 + 1] : 0.0f;
            w.z = (s_q[b0 + 2] == ent) ? s_d[b0 + 2] : 0.0f;
            w.w = (s_q[b0 + 3] == ent) ? s_d[b0 + 3] : 0.0f;
            ((float4*)memA)[i4] = w;
        }
    }
    gridbar(bar, 0);

    // ---- P1: step-0 scatter (analytic one-hot gather) into memA ----
    {
        float(*sattn)[N_REL + 1] = (float(*)[N_REL + 1])s_raw;
        for (int idx = tid; idx < NB * N_REL; idx += NTHR) {
            int b = idx / N_REL, r = idx % N_REL;
            sattn[b][r] = attn[b * (BODY_LEN * N_REL) + 0 * N_REL + r];
        }
        __syncthreads();
        int myqh = qh[lane];
        scan_scatter<true>(ep, nullptr, nullptr, memA, sattn, nE, lane, myqh, wave, nW);
    }
    gridbar(bar, 1);

    for (int s = 1; s < BODY_LEN; ++s) {
        const bool last = (s == BODY_LEN - 1);
        const float* cur = (s == 1) ? memA : memB;
        float* nxt = (s == 1) ? memB : memA;
        // ---- decay cur -> nxt; build activity mask; (last: accumulate sums) ----
        {
            float* s_d = (float*)s_raw;
            float* s_s = (float*)(s_raw + 256);
            if (tid < NB) {
                s_d[tid] = attn[tid * (BODY_LEN * N_REL) + s * N_REL + (N_REL - 1)];
                s_s[tid] = 0.0f;
            }
            __syncthreads();
            int b0 = (tid * 4) & 63;
            float4 acc = {0.0f, 0.0f, 0.0f, 0.0f};
            for (int i4 = gtid; i4 < total4; i4 += gsz) {
                float4 v = ((const float4*)cur)[i4];
                float4 w;
                w.x = v.x * s_d[b0 + 0];
                w.y = v.y * s_d[b0 + 1];
                w.z = v.z * s_d[b0 + 2];
                w.w = v.w * s_d[b0 + 3];
                ((float4*)nxt)[i4] = w;
                if (last) { acc.x += w.x; acc.y += w.y; acc.z += w.z; acc.w += w.w; }
                unsigned nib = (unsigned)(v.x != 0.0f) | ((unsigned)(v.y != 0.0f) << 1) |
                               ((unsigned)(v.z != 0.0f) << 2) | ((unsigned)(v.w != 0.0f) << 3);
                unsigned long long m = (unsigned long long)nib << (4 * (lane & 15));
#pragma unroll
                for (int off = 1; off < 16; off <<= 1)
                    m |= (unsigned long long)__shfl_xor((long long)m, off, 16);
                if ((lane & 15) == 0) act[i4 >> 4] = m;
            }
            if (last) {
                atomicAdd(&s_s[b0 + 0], acc.x);
                atomicAdd(&s_s[b0 + 1], acc.y);
                atomicAdd(&s_s[b0 + 2], acc.z);
                atomicAdd(&s_s[b0 + 3], acc.w);
                __syncthreads();
                if (tid < NB) atomicAdd(&sums[tid], s_s[tid]);
            }
        }
        gridbar(bar, 2 * s);
        // ---- scatter: mask-gated gathers from cur, atomics into nxt ----
        {
            float(*sattn)[N_REL + 1] = (float(*)[N_REL + 1])s_raw;
            float* s_s = (float*)(s_raw + 64 * (N_REL + 1) * 4);
            for (int idx = tid; idx < NB * N_REL; idx += NTHR) {
                int b = idx / N_REL, r = idx % N_REL;
                sattn[b][r] = attn[b * (BODY_LEN * N_REL) + s * N_REL + r];
            }
            if (tid < NB) s_s[tid] = 0.0f;
            __syncthreads();
            float lsum = scan_scatter<false>(ep, act, cur, nxt, sattn, nE, lane, 0, wave, nW);
            if (last) {
                atomicAdd(&s_s[lane], lsum);
                __syncthreads();
                if (tid < NB) atomicAdd(&sums[tid], s_s[tid]);
            }
        }
        gridbar(bar, 2 * s + 1);
    }
    // final state in memA; sums complete

    // ---- P7: transpose + normalize + loss ----
    {
        float(*tile)[65] = (float(*)[65])s_raw;
        float* s_inv = (float*)(s_raw + 64 * 65 * 4);
        if (blockIdx.x < N_ENT / 64) {
            int e0 = blockIdx.x * 64;
            if (tid < 64) s_inv[tid] = 1.0f / fmaxf(THR, sums[tid]);
            const float4* m4 = (const float4*)(memA + (size_t)e0 * 64);
#pragma unroll
            for (int k = 0; k < 4; ++k) {
                int i4 = k * 256 + tid;
                float4 v = m4[i4];
                int el = i4 >> 4, b0 = (i4 * 4) & 63;
                tile[el][b0 + 0] = v.x; tile[el][b0 + 1] = v.y;
                tile[el][b0 + 2] = v.z; tile[el][b0 + 3] = v.w;
            }
            __syncthreads();
#pragma unroll
            for (int k = 0; k < 16; ++k) {
                int idx = k * 256 + tid;
                int el = idx & 63, b = idx >> 6;
                out[1 + (size_t)b * N_ENT + e0 + el] = tile[el][b] * s_inv[b];
            }
        } else if (blockIdx.x == N_ENT / 64) {
            int b = tid;
            if (b < 64) {
                float p = memA[(size_t)tt[b] * 64 + b] / fmaxf(THR, sums[b]);
                float l = -logf(fmaxf(THR, p));
#pragma unroll
                for (int off = 32; off > 0; off >>= 1) l += __shfl_down(l, off);
                if (b == 0) out[0] = l * (1.0f / 64.0f);
            }
        }
    }
}

extern "C" void kernel_launch(void* const* d_in, const int* in_sizes, int n_in,
                              void* d_out, int out_size, void* d_ws, size_t ws_size,
                              hipStream_t stream) {
    const int*   qh   = (const int*)d_in[0];
    const int*   qr   = (const int*)d_in[1];
    const int*   tt   = (const int*)d_in[2];
    const float* attn = (const float*)d_in[3];
    const int*   eh   = (const int*)d_in[4];
    const int*   et   = (const int*)d_in[5];
    const int*   er   = (const int*)d_in[6];
    const float* ev   = (const float*)d_in[7];
    float* out = (float*)d_out;
    int nE = in_sizes[4];

    char* ws = (char*)d_ws;
    int4*               ep   = (int4*)ws;                                  // 4.8 MB
    float*              sums = (float*)(ws + (6u << 20));                  // 256 B
    unsigned*           bar  = (unsigned*)(ws + (6u << 20) + 256);         // 32 B (8 phases)
    unsigned long long* act  = (unsigned long long*)(ws + (6u << 20) + 4096);  // 320 KB
    float* memA = (float*)(ws + (8u << 20));                               // 10.24 MB
    float* memB = (float*)(ws + (8u << 20) + 10240000u);                   // 10.24 MB

    // zero barrier counters (+ sums, also zeroed in-kernel) — ws is poisoned 0xAA
    hipMemsetAsync(ws + (6u << 20), 0, 512, stream);

    k_all<<<NBLK, NTHR, 0, stream>>>(qh, qr, tt, attn, eh, et, er, ev,
                                     ep, sums, bar, act, memA, memB, out, nE);
}

// Round 6
// 503.842 us; speedup vs baseline: 3.3284x; 2.2405x over previous
//
#include <hip/hip_runtime.h>
#include <hip/hip_bf16.h>

#define N_ENT 40000
#define NB 64
#define BODY_LEN 3
#define N_REL 48
#define NUM_POS 24
#define THR 1e-20f
#define NBLK 1024
#define NTHR 256

typedef unsigned long long u64;

// All cross-phase global data uses relaxed AGENT-scope atomics (sc1 cache-bypass,
// coherent at device coherence point) -> NO __threadfence (L2 cache-walks) needed.
__device__ __forceinline__ u64 ald64(const u64* p) {
    return __hip_atomic_load((u64*)p, __ATOMIC_RELAXED, __HIP_MEMORY_SCOPE_AGENT);
}
__device__ __forceinline__ void ast64(u64* p, u64 v) {
    __hip_atomic_store(p, v, __ATOMIC_RELAXED, __HIP_MEMORY_SCOPE_AGENT);
}
__device__ __forceinline__ float aldf(const float* p) {
    return __hip_atomic_load((float*)p, __ATOMIC_RELAXED, __HIP_MEMORY_SCOPE_AGENT);
}
__device__ __forceinline__ void astf(float* p, float v) {
    __hip_atomic_store(p, v, __ATOMIC_RELAXED, __HIP_MEMORY_SCOPE_AGENT);
}

// Fence-free grid barrier: __syncthreads drains vmcnt (all sc1 stores reach the
// coherence point) before thread0 arrives. All 1024 blocks co-resident (4/CU).
__device__ __forceinline__ void gridbar(unsigned* bar, int phase) {
    __syncthreads();
    if (threadIdx.x == 0) {
        __hip_atomic_fetch_add(&bar[phase], 1u, __ATOMIC_RELAXED, __HIP_MEMORY_SCOPE_AGENT);
        while (__hip_atomic_load(&bar[phase], __ATOMIC_RELAXED, __HIP_MEMORY_SCOPE_AGENT) < NBLK)
            __builtin_amdgcn_s_sleep(16);
    }
    __syncthreads();
}

// Returns this lane's total scattered contribution (for final-step sums).
template <bool STEP0>
__device__ __forceinline__ float scan_scatter(
    const u64* __restrict__ epHT, const u64* __restrict__ epRV,
    const u64* __restrict__ act,
    const float* __restrict__ oldm, float* __restrict__ nxt,
    const float (*__restrict__ sattn)[N_REL + 1],
    int nE, int lane, int myqh, int wave, int nW) {
    float lsum = 0.0f;
    int e = wave;
    for (; e + nW < nE; e += 2 * nW) {
        u64 ht0 = ald64(&epHT[e]);
        u64 rv0 = ald64(&epRV[e]);
        u64 ht1 = ald64(&epHT[e + nW]);
        u64 rv1 = ald64(&epRV[e + nW]);
        int h0 = (int)(unsigned)ht0, t0 = (int)(ht0 >> 32), r0 = (int)(unsigned)rv0;
        int h1 = (int)(unsigned)ht1, t1 = (int)(ht1 >> 32), r1 = (int)(unsigned)rv1;
        float v0 = __uint_as_float((unsigned)(rv0 >> 32));
        float v1 = __uint_as_float((unsigned)(rv1 >> 32));
        if (STEP0) {
            bool hh = (h0 == myqh), ht = (t0 == myqh);
            if (__ballot(hh || ht) != 0ULL && v0 != 0.0f) {
                float c1 = hh ? v0 * sattn[lane][r0] : 0.0f;
                float c2 = ht ? v0 * sattn[lane][r0 + NUM_POS] : 0.0f;
                if (c1 != 0.0f) atomicAdd(&nxt[(size_t)t0 * 64 + lane], c1);
                if (c2 != 0.0f) atomicAdd(&nxt[(size_t)h0 * 64 + lane], c2);
            }
            hh = (h1 == myqh); ht = (t1 == myqh);
            if (__ballot(hh || ht) != 0ULL && v1 != 0.0f) {
                float c1 = hh ? v1 * sattn[lane][r1] : 0.0f;
                float c2 = ht ? v1 * sattn[lane][r1 + NUM_POS] : 0.0f;
                if (c1 != 0.0f) atomicAdd(&nxt[(size_t)t1 * 64 + lane], c1);
                if (c2 != 0.0f) atomicAdd(&nxt[(size_t)h1 * 64 + lane], c2);
            }
        } else {
            u64 ah0 = ald64(&act[h0]), at0 = ald64(&act[t0]);
            u64 ah1 = ald64(&act[h1]), at1 = ald64(&act[t1]);
            if (((ah0 | at0) != 0ULL) && v0 != 0.0f) {
                bool hh = (ah0 >> lane) & 1ULL, ht = (at0 >> lane) & 1ULL;
                float c1 = hh ? aldf(&oldm[(size_t)h0 * 64 + lane]) * v0 * sattn[lane][r0] : 0.0f;
                float c2 = ht ? aldf(&oldm[(size_t)t0 * 64 + lane]) * v0 * sattn[lane][r0 + NUM_POS] : 0.0f;
                if (c1 != 0.0f) { atomicAdd(&nxt[(size_t)t0 * 64 + lane], c1); lsum += c1; }
                if (c2 != 0.0f) { atomicAdd(&nxt[(size_t)h0 * 64 + lane], c2); lsum += c2; }
            }
            if (((ah1 | at1) != 0ULL) && v1 != 0.0f) {
                bool hh = (ah1 >> lane) & 1ULL, ht = (at1 >> lane) & 1ULL;
                float c1 = hh ? aldf(&oldm[(size_t)h1 * 64 + lane]) * v1 * sattn[lane][r1] : 0.0f;
                float c2 = ht ? aldf(&oldm[(size_t)t1 * 64 + lane]) * v1 * sattn[lane][r1 + NUM_POS] : 0.0f;
                if (c1 != 0.0f) { atomicAdd(&nxt[(size_t)t1 * 64 + lane], c1); lsum += c1; }
                if (c2 != 0.0f) { atomicAdd(&nxt[(size_t)h1 * 64 + lane], c2); lsum += c2; }
            }
        }
    }
    for (; e < nE; e += nW) {
        u64 ht0 = ald64(&epHT[e]);
        u64 rv0 = ald64(&epRV[e]);
        int h = (int)(unsigned)ht0, t = (int)(ht0 >> 32), r = (int)(unsigned)rv0;
        float v = __uint_as_float((unsigned)(rv0 >> 32));
        if (STEP0) {
            bool hh = (h == myqh), ht = (t == myqh);
            if (__ballot(hh || ht) == 0ULL || v == 0.0f) continue;
            float c1 = hh ? v * sattn[lane][r] : 0.0f;
            float c2 = ht ? v * sattn[lane][r + NUM_POS] : 0.0f;
            if (c1 != 0.0f) atomicAdd(&nxt[(size_t)t * 64 + lane], c1);
            if (c2 != 0.0f) atomicAdd(&nxt[(size_t)h * 64 + lane], c2);
        } else {
            u64 ah = ald64(&act[h]), at = ald64(&act[t]);
            if (((ah | at) == 0ULL) || v == 0.0f) continue;
            bool hh = (ah >> lane) & 1ULL, htb = (at >> lane) & 1ULL;
            float c1 = hh ? aldf(&oldm[(size_t)h * 64 + lane]) * v * sattn[lane][r] : 0.0f;
            float c2 = htb ? aldf(&oldm[(size_t)t * 64 + lane]) * v * sattn[lane][r + NUM_POS] : 0.0f;
            if (c1 != 0.0f) { atomicAdd(&nxt[(size_t)t * 64 + lane], c1); lsum += c1; }
            if (c2 != 0.0f) { atomicAdd(&nxt[(size_t)h * 64 + lane], c2); lsum += c2; }
        }
    }
    return lsum;
}

__global__ __launch_bounds__(NTHR, 4) void k_all(
    const int* __restrict__ qh, const int* __restrict__ qr, const int* __restrict__ tt,
    const float* __restrict__ attn,
    const int* __restrict__ eh, const int* __restrict__ et, const int* __restrict__ er,
    const float* __restrict__ ev,
    u64* __restrict__ epHT, u64* __restrict__ epRV,
    float* __restrict__ sums, unsigned* __restrict__ bar, u64* __restrict__ act,
    float* __restrict__ memA, float* __restrict__ memB, float* __restrict__ out, int nE) {
    __shared__ __align__(16) unsigned char s_raw[(64 * 65 + 64) * 4];  // 16.9 KB

    const int tid = threadIdx.x;
    const int lane = tid & 63;
    const int gtid = blockIdx.x * NTHR + tid;
    const int gsz = NBLK * NTHR;          // 262144
    const int wave = gtid >> 6;
    const int nW = gsz >> 6;              // 4096
    const int total2 = NB * N_ENT / 2;    // 1,280,000 (u64 pairs)

    // ---- P0: kill-mask + pack edges; memA = D0 * one_hot(qh); zero sums ----
    {
        long long* s_key = (long long*)s_raw;
        float* s_d = (float*)(s_raw + 512);
        int* s_q = (int*)(s_raw + 512 + 256);
        if (tid < NB) {
            s_key[tid] = ((long long)qh[tid] << 32) | ((long long)tt[tid] << 8) | (long long)qr[tid];
            s_d[tid] = attn[tid * (BODY_LEN * N_REL) + 0 * N_REL + (N_REL - 1)];
            s_q[tid] = qh[tid];
        }
        if (gtid < NB) astf(&sums[gtid], 0.0f);
        __syncthreads();
        for (int i = gtid; i < nE; i += gsz) {
            int h = eh[i], t = et[i], r = er[i];
            long long k = ((long long)h << 32) | ((long long)t << 8) | (long long)r;
            bool killed = false;
#pragma unroll
            for (int b = 0; b < NB; ++b) killed |= (s_key[b] == k);
            float v = killed ? 0.0f : ev[i];
            ast64(&epHT[i], (u64)(unsigned)h | ((u64)(unsigned)t << 32));
            ast64(&epRV[i], (u64)(unsigned)r | ((u64)__float_as_uint(v) << 32));
        }
        int b0 = (tid * 2) & 63;
        for (int i2 = gtid; i2 < total2; i2 += gsz) {
            int ent = i2 >> 5;
            float wx = (s_q[b0 + 0] == ent) ? s_d[b0 + 0] : 0.0f;
            float wy = (s_q[b0 + 1] == ent) ? s_d[b0 + 1] : 0.0f;
            ast64(&((u64*)memA)[i2], (u64)__float_as_uint(wx) | ((u64)__float_as_uint(wy) << 32));
        }
    }
    gridbar(bar, 0);

    // ---- P1: step-0 scatter (analytic one-hot gather) into memA ----
    {
        float(*sattn)[N_REL + 1] = (float(*)[N_REL + 1])s_raw;
        for (int idx = tid; idx < NB * N_REL; idx += NTHR) {
            int b = idx / N_REL, r = idx % N_REL;
            sattn[b][r] = attn[b * (BODY_LEN * N_REL) + 0 * N_REL + r];
        }
        __syncthreads();
        int myqh = qh[lane];
        scan_scatter<true>(epHT, epRV, nullptr, nullptr, memA, sattn, nE, lane, myqh, wave, nW);
    }
    gridbar(bar, 1);

    for (int s = 1; s < BODY_LEN; ++s) {
        const bool last = (s == BODY_LEN - 1);
        const float* cur = (s == 1) ? memA : memB;
        float* nxt = (s == 1) ? memB : memA;
        // ---- decay cur -> nxt; build activity mask; (last: accumulate sums) ----
        {
            float* s_d = (float*)s_raw;
            float* s_s = (float*)(s_raw + 256);
            if (tid < NB) {
                s_d[tid] = attn[tid * (BODY_LEN * N_REL) + s * N_REL + (N_REL - 1)];
                s_s[tid] = 0.0f;
            }
            __syncthreads();
            int b0 = (tid * 2) & 63;
            float accx = 0.0f, accy = 0.0f;
            int sub = lane & 31;  // 32 lanes cover one entity (32 u64 = 64 floats)
            for (int i2 = gtid; i2 < total2; i2 += gsz) {
                u64 p = ald64(&((const u64*)cur)[i2]);
                float vx = __uint_as_float((unsigned)p);
                float vy = __uint_as_float((unsigned)(p >> 32));
                float wx = vx * s_d[b0 + 0];
                float wy = vy * s_d[b0 + 1];
                ast64(&((u64*)nxt)[i2], (u64)__float_as_uint(wx) | ((u64)__float_as_uint(wy) << 32));
                if (last) { accx += wx; accy += wy; }
                u64 m = ((u64)((vx != 0.0f) | ((vy != 0.0f) << 1))) << (2 * sub);
#pragma unroll
                for (int off = 1; off < 32; off <<= 1)
                    m |= (u64)__shfl_xor((long long)m, off, 32);
                if (sub == 0) ast64(&act[i2 >> 5], m);
            }
            if (last) {
                atomicAdd(&s_s[b0 + 0], accx);
                atomicAdd(&s_s[b0 + 1], accy);
                __syncthreads();
                if (tid < NB) atomicAdd(&sums[tid], s_s[tid]);
            }
        }
        gridbar(bar, 2 * s);
        // ---- scatter: mask-gated gathers from cur, atomics into nxt ----
        {
            float(*sattn)[N_REL + 1] = (float(*)[N_REL + 1])s_raw;
            float* s_s = (float*)(s_raw + 64 * (N_REL + 1) * 4);
            for (int idx = tid; idx < NB * N_REL; idx += NTHR) {
                int b = idx / N_REL, r = idx % N_REL;
                sattn[b][r] = attn[b * (BODY_LEN * N_REL) + s * N_REL + r];
            }
            if (tid < NB) s_s[tid] = 0.0f;
            __syncthreads();
            float lsum = scan_scatter<false>(epHT, epRV, act, cur, nxt, sattn, nE, lane, 0, wave, nW);
            if (last) {
                atomicAdd(&s_s[lane], lsum);
                __syncthreads();
                if (tid < NB) atomicAdd(&sums[tid], s_s[tid]);
            }
        }
        gridbar(bar, 2 * s + 1);
    }
    // final state in memA; sums complete

    // ---- P7: transpose + normalize + loss ----
    {
        float(*tile)[65] = (float(*)[65])s_raw;
        float* s_inv = (float*)(s_raw + 64 * 65 * 4);
        if (blockIdx.x < N_ENT / 64) {
            int e0 = blockIdx.x * 64;
            if (tid < 64) s_inv[tid] = 1.0f / fmaxf(THR, aldf(&sums[tid]));
            const u64* m2 = (const u64*)(memA + (size_t)e0 * 64);
#pragma unroll
            for (int k = 0; k < 8; ++k) {
                int i2 = k * 256 + tid;           // 2048 u64 = 4096 floats
                u64 p = ald64(&m2[i2]);
                int el = i2 >> 5, b0 = (i2 * 2) & 63;
                tile[el][b0 + 0] = __uint_as_float((unsigned)p);
                tile[el][b0 + 1] = __uint_as_float((unsigned)(p >> 32));
            }
            __syncthreads();
#pragma unroll
            for (int k = 0; k < 16; ++k) {
                int idx = k * 256 + tid;
                int el = idx & 63, b = idx >> 6;
                out[1 + (size_t)b * N_ENT + e0 + el] = tile[el][b] * s_inv[b];
            }
        } else if (blockIdx.x == N_ENT / 64) {
            int b = tid;
            if (b < 64) {
                float p = aldf(&memA[(size_t)tt[b] * 64 + b]) / fmaxf(THR, aldf(&sums[b]));
                float l = -logf(fmaxf(THR, p));
#pragma unroll
                for (int off = 32; off > 0; off >>= 1) l += __shfl_down(l, off);
                if (b == 0) out[0] = l * (1.0f / 64.0f);
            }
        }
    }
}

extern "C" void kernel_launch(void* const* d_in, const int* in_sizes, int n_in,
                              void* d_out, int out_size, void* d_ws, size_t ws_size,
                              hipStream_t stream) {
    const int*   qh   = (const int*)d_in[0];
    const int*   qr   = (const int*)d_in[1];
    const int*   tt   = (const int*)d_in[2];
    const float* attn = (const float*)d_in[3];
    const int*   eh   = (const int*)d_in[4];
    const int*   et   = (const int*)d_in[5];
    const int*   er   = (const int*)d_in[6];
    const float* ev   = (const float*)d_in[7];
    float* out = (float*)d_out;
    int nE = in_sizes[4];

    char* ws = (char*)d_ws;
    u64*      epHT = (u64*)ws;                            // 2.4 MB
    u64*      epRV = (u64*)(ws + (3u << 20));             // 2.4 MB
    float*    sums = (float*)(ws + (6u << 20));           // 256 B
    unsigned* bar  = (unsigned*)(ws + (6u << 20) + 256);  // 32 B (8 phases)
    u64*      act  = (u64*)(ws + (6u << 20) + 4096);      // 320 KB
    float*    memA = (float*)(ws + (8u << 20));           // 10.24 MB
    float*    memB = (float*)(ws + (8u << 20) + 10240000u);

    // zero barrier counters (ws is re-poisoned to 0xAA before every launch)
    hipMemsetAsync(ws + (6u << 20), 0, 512, stream);

    k_all<<<NBLK, NTHR, 0, stream>>>(qh, qr, tt, attn, eh, et, er, ev,
                                     epHT, epRV, sums, bar, act, memA, memB, out, nE);
}

// Round 7
// 316.022 us; speedup vs baseline: 5.3066x; 1.5943x over previous
//
#include <hip/hip_runtime.h>
#include <hip/hip_bf16.h>

#define N_ENT 40000
#define NB 64
#define BODY_LEN 3
#define N_REL 48
#define NUM_POS 24
#define THR 1e-20f

typedef unsigned long long u64;

// mem layout: entity-major, mem[ent*64 + b]
// edges packed: epHT[i] = head | tail<<32 ; epRV[i] = rel | bits(val)<<32

// ---- 1. prep: kill-mask + pack edges + memA = D0*one_hot(qh) + zero sums ----
__global__ void k_prep(const int* __restrict__ qh, const int* __restrict__ qr,
                       const int* __restrict__ tt, const float* __restrict__ attn,
                       const int* __restrict__ eh, const int* __restrict__ et,
                       const int* __restrict__ er, const float* __restrict__ ev,
                       u64* __restrict__ epHT, u64* __restrict__ epRV,
                       float* __restrict__ memA, float* __restrict__ sums, int nE) {
    __shared__ long long s_key[NB];
    __shared__ float s_d[NB];
    __shared__ int s_q[NB];
    int tid = threadIdx.x;
    int gtid = blockIdx.x * 256 + tid;
    int gsz = gridDim.x * 256;
    if (tid < NB) {
        s_key[tid] = ((long long)qh[tid] << 32) | ((long long)tt[tid] << 8) | (long long)qr[tid];
        s_d[tid] = attn[tid * (BODY_LEN * N_REL) + (N_REL - 1)];
        s_q[tid] = qh[tid];
    }
    if (gtid < NB) sums[gtid] = 0.0f;
    __syncthreads();
    for (int i = gtid; i < nE; i += gsz) {
        int h = eh[i], t = et[i], r = er[i];
        long long k = ((long long)h << 32) | ((long long)t << 8) | (long long)r;
        bool killed = false;
#pragma unroll
        for (int b = 0; b < NB; ++b) killed |= (s_key[b] == k);
        float v = killed ? 0.0f : ev[i];
        epHT[i] = (u64)(unsigned)h | ((u64)(unsigned)t << 32);
        epRV[i] = (u64)(unsigned)r | ((u64)__float_as_uint(v) << 32);
    }
    int b0 = (tid * 4) & 63;
    const int total4 = NB * N_ENT / 4;
    for (int i4 = gtid; i4 < total4; i4 += gsz) {
        int ent = i4 >> 4;
        float4 w;
        w.x = (s_q[b0 + 0] == ent) ? s_d[b0 + 0] : 0.0f;
        w.y = (s_q[b0 + 1] == ent) ? s_d[b0 + 1] : 0.0f;
        w.z = (s_q[b0 + 2] == ent) ? s_d[b0 + 2] : 0.0f;
        w.w = (s_q[b0 + 3] == ent) ? s_d[b0 + 3] : 0.0f;
        ((float4*)memA)[i4] = w;
    }
}

// ---- 2. step-0 scatter: analytic one-hot source ----
__global__ __launch_bounds__(256) void k_scatter0(
    const u64* __restrict__ epHT, const u64* __restrict__ epRV,
    const float* __restrict__ attn, const int* __restrict__ qh,
    float* __restrict__ nxt, int nE) {
    __shared__ float sattn[NB][N_REL + 1];
    int tid = threadIdx.x;
    for (int idx = tid; idx < NB * N_REL; idx += 256) {
        int b = idx / N_REL, r = idx % N_REL;
        sattn[b][r] = attn[b * (BODY_LEN * N_REL) + r];
    }
    __syncthreads();
    int lane = tid & 63;
    int myqh = qh[lane];
    int wave = (blockIdx.x * 256 + tid) >> 6;
    int nW = (gridDim.x * 256) >> 6;
    for (int e = wave; e < nE; e += nW) {
        u64 ht = epHT[e];
        int h = (int)(unsigned)ht, t = (int)(ht >> 32);
        bool hh = (h == myqh), tb = (t == myqh);
        if (__ballot(hh || tb) == 0ULL) continue;
        u64 rv = epRV[e];
        int r = (int)(unsigned)rv;
        float v = __uint_as_float((unsigned)(rv >> 32));
        if (v == 0.0f) continue;
        float c1 = hh ? v * sattn[lane][r] : 0.0f;
        float c2 = tb ? v * sattn[lane][r + NUM_POS] : 0.0f;
        if (c1 != 0.0f) atomicAdd(&nxt[(size_t)t * 64 + lane], c1);
        if (c2 != 0.0f) atomicAdd(&nxt[(size_t)h * 64 + lane], c2);
    }
}

// ---- 3/5. decay cur->nxt + per-(entity,batch) u64 activity mask (+sums if LAST) ----
template <bool LAST>
__global__ void k_decay_mask(const float* __restrict__ cur, float* __restrict__ nxt,
                             const float* __restrict__ attn, int step,
                             u64* __restrict__ act, float* __restrict__ sums) {
    __shared__ float s_d[NB];
    __shared__ float s_s[NB];
    int tid = threadIdx.x;
    if (tid < NB) {
        s_d[tid] = attn[tid * (BODY_LEN * N_REL) + step * N_REL + (N_REL - 1)];
        if (LAST) s_s[tid] = 0.0f;
    }
    __syncthreads();
    int lane = tid & 63;
    int b0 = (tid * 4) & 63;
    int i4 = blockIdx.x * 256 + tid;   // one pass: grid sized exactly
    float4 v = ((const float4*)cur)[i4];
    float4 w;
    w.x = v.x * s_d[b0 + 0];
    w.y = v.y * s_d[b0 + 1];
    w.z = v.z * s_d[b0 + 2];
    w.w = v.w * s_d[b0 + 3];
    ((float4*)nxt)[i4] = w;
    unsigned nib = (unsigned)(v.x != 0.0f) | ((unsigned)(v.y != 0.0f) << 1) |
                   ((unsigned)(v.z != 0.0f) << 2) | ((unsigned)(v.w != 0.0f) << 3);
    u64 m = (u64)nib << (4 * (lane & 15));
#pragma unroll
    for (int off = 1; off < 16; off <<= 1)
        m |= (u64)__shfl_xor((long long)m, off, 16);
    if ((lane & 15) == 0) act[i4 >> 4] = m;
    if (LAST) {
        atomicAdd(&s_s[b0 + 0], w.x);
        atomicAdd(&s_s[b0 + 1], w.y);
        atomicAdd(&s_s[b0 + 2], w.z);
        atomicAdd(&s_s[b0 + 3], w.w);
        __syncthreads();
        if (tid < NB) atomicAdd(&sums[tid], s_s[tid]);
    }
}

// ---- 4/6. scatter: lane-gated gathers from cur, atomics into nxt (+sums if LAST) ----
template <bool LAST>
__global__ __launch_bounds__(256) void k_scatter(
    const u64* __restrict__ epHT, const u64* __restrict__ epRV,
    const u64* __restrict__ act, const float* __restrict__ attn, int step,
    const float* __restrict__ cur, float* __restrict__ nxt,
    float* __restrict__ sums, int nE) {
    __shared__ float sattn[NB][N_REL + 1];
    __shared__ float s_s[NB];
    int tid = threadIdx.x;
    for (int idx = tid; idx < NB * N_REL; idx += 256) {
        int b = idx / N_REL, r = idx % N_REL;
        sattn[b][r] = attn[b * (BODY_LEN * N_REL) + step * N_REL + r];
    }
    if (LAST && tid < NB) s_s[tid] = 0.0f;
    __syncthreads();
    int lane = tid & 63;
    int wave = (blockIdx.x * 256 + tid) >> 6;
    int nW = (gridDim.x * 256) >> 6;
    float lsum = 0.0f;
    int e = wave;
    for (; e + nW < nE; e += 2 * nW) {
        u64 ht0 = epHT[e], ht1 = epHT[e + nW];
        int h0 = (int)(unsigned)ht0, t0 = (int)(ht0 >> 32);
        int h1 = (int)(unsigned)ht1, t1 = (int)(ht1 >> 32);
        u64 ah0 = act[h0], at0 = act[t0];
        u64 ah1 = act[h1], at1 = act[t1];
        if ((ah0 | at0) != 0ULL) {
            u64 rv = epRV[e];
            int r = (int)(unsigned)rv;
            float v = __uint_as_float((unsigned)(rv >> 32));
            if (v != 0.0f) {
                float c1 = 0.0f, c2 = 0.0f;
                if ((ah0 >> lane) & 1ULL) c1 = cur[(size_t)h0 * 64 + lane] * v * sattn[lane][r];
                if ((at0 >> lane) & 1ULL) c2 = cur[(size_t)t0 * 64 + lane] * v * sattn[lane][r + NUM_POS];
                if (c1 != 0.0f) { atomicAdd(&nxt[(size_t)t0 * 64 + lane], c1); if (LAST) lsum += c1; }
                if (c2 != 0.0f) { atomicAdd(&nxt[(size_t)h0 * 64 + lane], c2); if (LAST) lsum += c2; }
            }
        }
        if ((ah1 | at1) != 0ULL) {
            u64 rv = epRV[e + nW];
            int r = (int)(unsigned)rv;
            float v = __uint_as_float((unsigned)(rv >> 32));
            if (v != 0.0f) {
                float c1 = 0.0f, c2 = 0.0f;
                if ((ah1 >> lane) & 1ULL) c1 = cur[(size_t)h1 * 64 + lane] * v * sattn[lane][r];
                if ((at1 >> lane) & 1ULL) c2 = cur[(size_t)t1 * 64 + lane] * v * sattn[lane][r + NUM_POS];
                if (c1 != 0.0f) { atomicAdd(&nxt[(size_t)t1 * 64 + lane], c1); if (LAST) lsum += c1; }
                if (c2 != 0.0f) { atomicAdd(&nxt[(size_t)h1 * 64 + lane], c2); if (LAST) lsum += c2; }
            }
        }
    }
    for (; e < nE; e += nW) {
        u64 ht = epHT[e];
        int h = (int)(unsigned)ht, t = (int)(ht >> 32);
        u64 ah = act[h], at = act[t];
        if ((ah | at) == 0ULL) continue;
        u64 rv = epRV[e];
        int r = (int)(unsigned)rv;
        float v = __uint_as_float((unsigned)(rv >> 32));
        if (v == 0.0f) continue;
        float c1 = 0.0f, c2 = 0.0f;
        if ((ah >> lane) & 1ULL) c1 = cur[(size_t)h * 64 + lane] * v * sattn[lane][r];
        if ((at >> lane) & 1ULL) c2 = cur[(size_t)t * 64 + lane] * v * sattn[lane][r + NUM_POS];
        if (c1 != 0.0f) { atomicAdd(&nxt[(size_t)t * 64 + lane], c1); if (LAST) lsum += c1; }
        if (c2 != 0.0f) { atomicAdd(&nxt[(size_t)h * 64 + lane], c2); if (LAST) lsum += c2; }
    }
    if (LAST) {
        atomicAdd(&s_s[lane], lsum);
        __syncthreads();
        if (tid < NB) atomicAdd(&sums[tid], s_s[tid]);
    }
}

// ---- 7. transpose + normalize + loss ----
__global__ void k_norm_tr(const float* __restrict__ mem, const float* __restrict__ sums,
                          const int* __restrict__ tt, float* __restrict__ out) {
    if (blockIdx.x == N_ENT / 64) {
        int b = threadIdx.x;
        if (b < 64) {
            float p = mem[(size_t)tt[b] * 64 + b] / fmaxf(THR, sums[b]);
            float l = -logf(fmaxf(THR, p));
#pragma unroll
            for (int off = 32; off > 0; off >>= 1) l += __shfl_down(l, off);
            if (b == 0) out[0] = l * (1.0f / 64.0f);
        }
        return;
    }
    __shared__ float tile[64][65];
    __shared__ float s_inv[64];
    int tid = threadIdx.x;
    int e0 = blockIdx.x * 64;
    if (tid < 64) s_inv[tid] = 1.0f / fmaxf(THR, sums[tid]);
    const float4* m4 = (const float4*)(mem + (size_t)e0 * 64);
#pragma unroll
    for (int k = 0; k < 4; ++k) {
        int i4 = k * 256 + tid;
        float4 v = m4[i4];
        int el = i4 >> 4, b0 = (i4 * 4) & 63;
        tile[el][b0 + 0] = v.x; tile[el][b0 + 1] = v.y;
        tile[el][b0 + 2] = v.z; tile[el][b0 + 3] = v.w;
    }
    __syncthreads();
#pragma unroll
    for (int k = 0; k < 16; ++k) {
        int idx = k * 256 + tid;
        int el = idx & 63, b = idx >> 6;
        out[1 + (size_t)b * N_ENT + e0 + el] = tile[el][b] * s_inv[b];
    }
}

extern "C" void kernel_launch(void* const* d_in, const int* in_sizes, int n_in,
                              void* d_out, int out_size, void* d_ws, size_t ws_size,
                              hipStream_t stream) {
    const int*   qh   = (const int*)d_in[0];
    const int*   qr   = (const int*)d_in[1];
    const int*   tt   = (const int*)d_in[2];
    const float* attn = (const float*)d_in[3];
    const int*   eh   = (const int*)d_in[4];
    const int*   et   = (const int*)d_in[5];
    const int*   er   = (const int*)d_in[6];
    const float* ev   = (const float*)d_in[7];
    float* out = (float*)d_out;
    int nE = in_sizes[4];

    char* ws = (char*)d_ws;
    u64*   epHT = (u64*)ws;                           // 2.4 MB
    u64*   epRV = (u64*)(ws + (3u << 20));            // 2.4 MB
    float* sums = (float*)(ws + (6u << 20));          // 256 B
    u64*   act  = (u64*)(ws + (6u << 20) + 4096);     // 320 KB
    float* memA = (float*)(ws + (8u << 20));          // 10.24 MB
    float* memB = (float*)(ws + (8u << 20) + 10240000u);

    const int NE_F4 = NB * N_ENT / 4 / 256;  // 2500 blocks, exact

    k_prep<<<2048, 256, 0, stream>>>(qh, qr, tt, attn, eh, et, er, ev,
                                     epHT, epRV, memA, sums, nE);
    k_scatter0<<<2048, 256, 0, stream>>>(epHT, epRV, attn, qh, memA, nE);
    k_decay_mask<false><<<NE_F4, 256, 0, stream>>>(memA, memB, attn, 1, act, sums);
    k_scatter<false><<<2048, 256, 0, stream>>>(epHT, epRV, act, attn, 1, memA, memB, sums, nE);
    k_decay_mask<true><<<NE_F4, 256, 0, stream>>>(memB, memA, attn, 2, act, sums);
    k_scatter<true><<<2048, 256, 0, stream>>>(epHT, epRV, act, attn, 2, memB, memA, sums, nE);
    k_norm_tr<<<N_ENT / 64 + 1, 256, 0, stream>>>(memA, sums, tt, out);
}